// Round 4
// baseline (272.168 us; speedup 1.0000x reference)
//
#include <hip/hip_runtime.h>
#include <stdint.h>

#define NUM_E 50000
#define EMBED_DIM 128
#define HID_DIM 200
#define BATCH 512
#define NN 50
#define HPAD 208   // 13*16 (x columns padded)
#define KPAD 224   // 7*32  (scores GEMM K padded)
#define NKT 7      // K tiles of 32
#define NTT2 3136  // N fragment tiles padded: 3136*16 = 50176 = 196*256
#define NXB 196    // grid.x for scores GEMM
#define PACK_BLOCKS 5488   // NTT2*NKT*64/256
#define XG_BLOCKS 400

typedef short s16x8 __attribute__((ext_vector_type(8)));
typedef float f32x4 __attribute__((ext_vector_type(4)));

__device__ inline unsigned short f2bf(float f) {
  union { float f; unsigned u; } v; v.f = f;
  unsigned r = v.u + 0x7FFF + ((v.u >> 16) & 1);
  return (unsigned short)(r >> 16);
}
__device__ inline float bf2f(unsigned short b) {
  union { unsigned u; float f; } v; v.u = ((unsigned)b) << 16;
  return v.f;
}

// async global->LDS, 16B per lane; lds dst = uniform base + lane*16
__device__ __forceinline__ void gl_lds16(const unsigned short* g, unsigned short* l) {
  __builtin_amdgcn_global_load_lds(
      (const __attribute__((address_space(1))) unsigned int*)g,
      (__attribute__((address_space(3))) unsigned int*)l, 16, 0, 0);
}

// ---------------------------------------------------------------------------
// Fused kernel: [0, PACK_BLOCKS)       -> pack mlp_w into B-fragment layout
//               [PACK_BLOCKS, +400)    -> x = gather(emb, idx) @ Ws_w^T + Ws_b
//               last block             -> zero S_ws
// ---------------------------------------------------------------------------
__global__ __launch_bounds__(256) void k_prep(
    const int* __restrict__ idx, const float* __restrict__ emb,
    const float* __restrict__ Ws_w, const float* __restrict__ Ws_b,
    const float* __restrict__ mlp_w,
    unsigned short* __restrict__ Bp, unsigned short* __restrict__ x_ws,
    float* __restrict__ sumsq_ws, float* __restrict__ S_ws)
{
  __shared__ unsigned short Al[64 * 40];
  __shared__ unsigned short Bl[208 * 40];
  const int bx = blockIdx.x;
  const int tid = threadIdx.x;

  if (bx < PACK_BLOCKS) {
    // ---- pack: Bp[((nt*7+kt)*64 + lane)*8 + j] ----
    const int t = bx * 256 + tid;
    const int lane = t & 63;
    const int f = t >> 6;
    const int kt = f % NKT;
    const int nt = f / NKT;
    const int n = nt * 16 + (lane & 15);
    const int kb = kt * 32 + (lane >> 4) * 8;
    unsigned short tmp[8] __attribute__((aligned(16)));
    if (n < NUM_E && kb < HID_DIM) {
      const float* src = mlp_w + (size_t)n * HID_DIM + kb;
      float4 f0 = *(const float4*)(src);
      float4 f1 = *(const float4*)(src + 4);
      tmp[0] = f2bf(f0.x); tmp[1] = f2bf(f0.y); tmp[2] = f2bf(f0.z); tmp[3] = f2bf(f0.w);
      tmp[4] = f2bf(f1.x); tmp[5] = f2bf(f1.y); tmp[6] = f2bf(f1.z); tmp[7] = f2bf(f1.w);
    } else {
      for (int j = 0; j < 8; j++) tmp[j] = 0;
    }
    *(uint4*)&Bp[(size_t)t * 8] = *(uint4*)tmp;
    return;
  }
  if (bx >= PACK_BLOCKS + XG_BLOCKS) {
    S_ws[tid] = 0.f;
    S_ws[256 + tid] = 0.f;
    return;
  }

  // ---- xgemm ----
  const int wave = tid >> 6, lane = tid & 63;
  const int q = lane >> 4, l15 = lane & 15;
  const int row0 = (bx - PACK_BLOCKS) * 64;

  f32x4 acc[13];
  for (int i = 0; i < 13; i++) acc[i] = (f32x4){0, 0, 0, 0};

  for (int kt = 0; kt < 4; ++kt) {
    const int k0 = kt * 32;
    {
      const int r = tid >> 2, q4 = tid & 3;
      const int erow = idx[row0 + r];
      const float* src = emb + (size_t)erow * EMBED_DIM + k0 + q4 * 8;
      float4 f0 = *(const float4*)(src);
      float4 f1 = *(const float4*)(src + 4);
      unsigned short tmp[8] __attribute__((aligned(16))) = {
        f2bf(f0.x), f2bf(f0.y), f2bf(f0.z), f2bf(f0.w),
        f2bf(f1.x), f2bf(f1.y), f2bf(f1.z), f2bf(f1.w)};
      *(uint4*)&Al[r * 40 + q4 * 8] = *(uint4*)tmp;
    }
    if (tid < 208) {
      unsigned short tmp[32] __attribute__((aligned(16)));
      if (tid < HID_DIM) {
        const float* src = Ws_w + (size_t)tid * EMBED_DIM + k0;
        for (int j = 0; j < 8; j++) {
          float4 f = *(const float4*)(src + j * 4);
          tmp[j*4+0] = f2bf(f.x); tmp[j*4+1] = f2bf(f.y);
          tmp[j*4+2] = f2bf(f.z); tmp[j*4+3] = f2bf(f.w);
        }
      } else {
        for (int j = 0; j < 32; j++) tmp[j] = 0;
      }
      for (int j = 0; j < 4; j++)
        *(uint4*)&Bl[tid * 40 + j * 8] = *(uint4*)&tmp[j * 8];
    }
    __syncthreads();
    s16x8 a = *(const s16x8*)&Al[(wave * 16 + l15) * 40 + q * 8];
    for (int ni = 0; ni < 13; ++ni) {
      s16x8 bfr = *(const s16x8*)&Bl[(ni * 16 + l15) * 40 + q * 8];
      acc[ni] = __builtin_amdgcn_mfma_f32_16x16x32_bf16(a, bfr, acc[ni], 0, 0, 0);
    }
    __syncthreads();
  }

  float sq[4] = {0, 0, 0, 0};
  for (int ni = 0; ni < 13; ++ni) {
    const int col = ni * 16 + l15;
    const bool cv = col < HID_DIM;
    const float bias = cv ? Ws_b[col] : 0.f;
    for (int p = 0; p < 4; p++) {
      float v = acc[ni][p] + bias;
      if (cv) sq[p] += v * v;
      const int grow = row0 + wave * 16 + q * 4 + p;
      x_ws[(size_t)grow * HPAD + col] = f2bf(cv ? v : 0.f);
    }
  }
  for (int m = 1; m < 16; m <<= 1)
    for (int p = 0; p < 4; p++) sq[p] += __shfl_xor(sq[p], m, 64);
  if (l15 == 0)
    for (int p = 0; p < 4; p++)
      sumsq_ws[row0 + wave * 16 + q * 4 + p] = sq[p];
}

// ---------------------------------------------------------------------------
// Kernel A2: routing. Emits Ap (A-fragment layout), fp32 poses, expa, D_b.
// ---------------------------------------------------------------------------
__global__ __launch_bounds__(256) void k_routing(
    const int* __restrict__ idx, const int* __restrict__ times,
    const unsigned short* __restrict__ x_ws, const float* __restrict__ sumsq_ws,
    unsigned short* __restrict__ Ap, float* __restrict__ poses_f,
    float* __restrict__ expa_ws, float* __restrict__ D_ws)
{
  __shared__ float u[NN * 201];
  __shared__ float cc[NN];
  __shared__ float bb[NN];
  __shared__ float vv[HID_DIM];
  __shared__ float nrm[NN];
  __shared__ int   sidx[NN];
  __shared__ float red[4];
  __shared__ float scaleS;
  const int tid = threadIdx.x;
  const int b = blockIdx.x;

  if (tid < NN) {
    nrm[tid] = fmaxf(sqrtf(sumsq_ws[b * NN + tid]), 1e-12f);
    sidx[tid] = idx[b * NN + tid];
    bb[tid] = 2.0f / (1.0f + (float)times[b * NN + tid]);
  }
  __syncthreads();
  // u-load: 4 threads per row, 50 cols each
  const int un = tid >> 2, uc0 = (tid & 3) * 50;
  if (un < NN) {
    const float inv = 1.0f / nrm[un];
    const unsigned short* xs = &x_ws[(size_t)(b * NN + un) * HPAD + uc0];
    for (int j = 0; j < 50; j++) u[un * 201 + uc0 + j] = bf2f(xs[j]) * inv;
  }
  __syncthreads();

  for (int it = 0; it < 3; ++it) {
    if (tid < 64) {
      float x = (tid < NN) ? bb[tid] : -1e30f;
      float m = x;
      for (int d = 1; d < 64; d <<= 1) m = fmaxf(m, __shfl_xor(m, d, 64));
      float e = (tid < NN) ? __expf(x - m) : 0.f;
      float s = e;
      for (int d = 1; d < 64; d <<= 1) s += __shfl_xor(s, d, 64);
      if (tid < NN) cc[tid] = e * (float)NN / s;
    }
    __syncthreads();
    float sh = 0.f;
    if (tid < HID_DIM)
      for (int n = 0; n < NN; n++) sh += cc[n] * u[n * 201 + tid];
    float sq = (tid < HID_DIM) ? sh * sh : 0.f;
    for (int d = 1; d < 64; d <<= 1) sq += __shfl_xor(sq, d, 64);
    if ((tid & 63) == 0) red[tid >> 6] = sq;
    __syncthreads();
    if (tid == 0) {
      const float t = red[0] + red[1] + red[2] + red[3];
      scaleS = t / (1.0f + t) / sqrtf(t + 1e-9f);
    }
    __syncthreads();
    if (tid < HID_DIM) vv[tid] = scaleS * sh;
    __syncthreads();
    if (it < 2) {
      // b-update: 4 threads per row, 50-length partial dots
      float d = 0.f;
      if (un < NN)
        for (int j = 0; j < 50; j++) d += u[un * 201 + uc0 + j] * vv[uc0 + j];
      d += __shfl_xor(d, 1, 64);
      d += __shfl_xor(d, 2, 64);
      if (un < NN && (tid & 3) == 0) bb[un] += d;
      __syncthreads();
    }
  }
  // poses scattered into A-fragment layout (zero-padded to KPAD)
  if (tid < KPAD) {
    const float val = (tid < HID_DIM) ? vv[tid] : 0.f;
    const int kt = tid >> 5, rem = tid & 31, q = rem >> 3, j = rem & 7;
    const int mt = b >> 4, l15 = b & 15;
    Ap[(size_t)(((mt * NKT + kt) * 64) + q * 16 + l15) * 8 + j] = f2bf(val);
  }
  if (tid < HID_DIM) poses_f[b * HID_DIM + tid] = vv[tid];
  // dedup of idx within row; D_b = NUM_E + sum_unique (exp(a)-1)
  if (tid < 64) {
    float a = 0.f; int first = 1;
    const int my = (tid < NN) ? sidx[tid] : -1;
    if (tid < NN) {
      for (int n = 0; n < NN; n++)
        if (sidx[n] == my) { a += cc[n]; if (n < tid) first = 0; }
      expa_ws[b * NN + tid] = __expf(a);
    }
    float contrib = (tid < NN && first) ? (__expf(a) - 1.0f) : 0.f;
    for (int d = 1; d < 64; d <<= 1) contrib += __shfl_xor(contrib, d, 64);
    if (tid == 0) D_ws[b] = (float)NUM_E + contrib;
  }
}

// ---------------------------------------------------------------------------
// Kernel G: GEMM, block tile 64M x 256N, K=224. A fragments register-direct
// from Ap (L2-resident); B-tile (16 KB) staged per kt via global_load_lds.
// PASS 0: S_b += sum exp(score).  PASS 1: out = log(0.5/D + 0.5*exp(s)/S).
// ---------------------------------------------------------------------------
template<int PASS>
__global__ __launch_bounds__(256, 4) void k_gemm(
    const unsigned short* __restrict__ Ap, const unsigned short* __restrict__ Bp,
    const float* __restrict__ mlp_b, const float* __restrict__ D_ws,
    float* __restrict__ S_ws, float* __restrict__ out)
{
  __shared__ __align__(16) unsigned short Bs[16 * 512];  // 16 KB
  __shared__ float red[256];
  const int tid = threadIdx.x;
  const int w = tid >> 6, lane = tid & 63;
  const int q = lane >> 4, l15 = lane & 15;
  const int mt0 = blockIdx.y * 4;
  const int m0 = blockIdx.y * 64;
  const int ntb = blockIdx.x * 16 + w * 4;   // wave's first nt tile

  if (PASS == 1 && tid < 64) {
    red[tid]      = 0.5f / D_ws[m0 + tid];
    red[64 + tid] = 0.5f / S_ws[m0 + tid];
  }
  float bias[4];
  #pragma unroll
  for (int nl = 0; nl < 4; ++nl) {
    const int col = (ntb + nl) * 16 + l15;
    bias[nl] = (col < NUM_E) ? mlp_b[col] : 0.f;
  }

  const unsigned short* apBase = Ap + (size_t)mt0 * NKT * 512;

  f32x4 acc[4][4];
  #pragma unroll
  for (int i = 0; i < 4; i++)
    #pragma unroll
    for (int j = 0; j < 4; j++) acc[i][j] = (f32x4){0, 0, 0, 0};

  for (int kt = 0; kt < NKT; ++kt) {
    #pragma unroll
    for (int nl = 0; nl < 4; ++nl)
      gl_lds16(Bp + ((size_t)(ntb + nl) * NKT + kt) * 512 + lane * 8,
               &Bs[(w * 4 + nl) * 512]);
    s16x8 a[4];
    #pragma unroll
    for (int mi = 0; mi < 4; ++mi)
      a[mi] = *(const s16x8*)&apBase[((mi * NKT + kt) * 64 + lane) * 8];
    __syncthreads();   // drains gl_lds (vmcnt 0) + the a-loads
    s16x8 bfr[4];
    #pragma unroll
    for (int nl = 0; nl < 4; ++nl)
      bfr[nl] = *(const s16x8*)&Bs[((w * 4 + nl) * 64 + lane) * 8];
    #pragma unroll
    for (int nl = 0; nl < 4; ++nl)
      #pragma unroll
      for (int mi = 0; mi < 4; ++mi)
        acc[mi][nl] = __builtin_amdgcn_mfma_f32_16x16x32_bf16(a[mi], bfr[nl], acc[mi][nl], 0, 0, 0);
    __syncthreads();   // all waves done reading Bs before next staging
  }

  if (PASS == 0) {
    float rs[4][4];
    #pragma unroll
    for (int mi = 0; mi < 4; mi++)
      #pragma unroll
      for (int p = 0; p < 4; p++) rs[mi][p] = 0.f;
    #pragma unroll
    for (int mi = 0; mi < 4; ++mi)
      #pragma unroll
      for (int nl = 0; nl < 4; ++nl) {
        const int col = (ntb + nl) * 16 + l15;
        #pragma unroll
        for (int p = 0; p < 4; p++) {
          const float v = acc[mi][nl][p] + bias[nl];
          rs[mi][p] += (col < NUM_E) ? __expf(v) : 0.f;
        }
      }
    #pragma unroll
    for (int m = 1; m < 16; m <<= 1)
      for (int mi = 0; mi < 4; mi++)
        for (int p = 0; p < 4; p++)
          rs[mi][p] += __shfl_xor(rs[mi][p], m, 64);
    if (l15 == 0)
      for (int mi = 0; mi < 4; mi++)
        for (int p = 0; p < 4; p++)
          red[w * 64 + mi * 16 + q * 4 + p] = rs[mi][p];
    __syncthreads();
    if (tid < 64)
      atomicAdd(&S_ws[m0 + tid],
                red[tid] + red[64 + tid] + red[128 + tid] + red[192 + tid]);
  } else {
    #pragma unroll
    for (int mi = 0; mi < 4; ++mi) {
      #pragma unroll
      for (int p = 0; p < 4; p++) {
        const int rl = mi * 16 + q * 4 + p;
        const float invD = red[rl];
        const float invS = red[64 + rl];
        const int row = m0 + rl;
        #pragma unroll
        for (int nl = 0; nl < 4; ++nl) {
          const int col = (ntb + nl) * 16 + l15;
          if (col < NUM_E) {
            const float v = acc[mi][nl][p] + bias[nl];
            out[(size_t)row * NUM_E + col] = __logf(fmaf(__expf(v), invS, invD));
          }
        }
      }
    }
  }
}

// ---------------------------------------------------------------------------
// Kernel D: fixup history positions; recompute score via fp32 dot product.
// One wave per (b, slot). Duplicate idx -> identical values, benign race.
// ---------------------------------------------------------------------------
__global__ __launch_bounds__(256) void k_fix(
    const int* __restrict__ idx, const float* __restrict__ expa,
    const float* __restrict__ poses_f, const float* __restrict__ mlp_w,
    const float* __restrict__ mlp_b, const float* __restrict__ D_ws,
    const float* __restrict__ S_ws, float* __restrict__ out)
{
  const int t = blockIdx.x * 4 + (threadIdx.x >> 6);
  const int lane = threadIdx.x & 63;
  if (t >= BATCH * NN) return;
  const int b = t / NN;
  const int j = idx[t];
  float dot = 0.f;
  for (int h = lane; h < HID_DIM; h += 64)
    dot += poses_f[b * HID_DIM + h] * mlp_w[(size_t)j * HID_DIM + h];
  for (int m = 1; m < 64; m <<= 1) dot += __shfl_xor(dot, m, 64);
  if (lane == 0) {
    const float s = dot + mlp_b[j];
    out[(size_t)b * NUM_E + j] = __logf(0.5f * expa[t] / D_ws[b] +
                                        0.5f * __expf(s) / S_ws[b]);
  }
}

extern "C" void kernel_launch(void* const* d_in, const int* in_sizes, int n_in,
                              void* d_out, int out_size, void* d_ws, size_t ws_size,
                              hipStream_t stream) {
  const int*   idx   = (const int*)d_in[0];
  const int*   times = (const int*)d_in[1];
  const float* emb   = (const float*)d_in[2];
  const float* Ws_w  = (const float*)d_in[3];
  const float* Ws_b  = (const float*)d_in[4];
  const float* mlp_w = (const float*)d_in[5];
  const float* mlp_b = (const float*)d_in[6];
  float* out = (float*)d_out;

  char* ws = (char*)d_ws;
  unsigned short* Bp    = (unsigned short*)ws; ws += (size_t)NTT2 * NKT * 64 * 8 * 2;  // 22.5 MB
  unsigned short* x_ws  = (unsigned short*)ws; ws += (size_t)BATCH * NN * HPAD * 2;    // 10.65 MB
  unsigned short* Ap    = (unsigned short*)ws; ws += (size_t)32 * NKT * 64 * 8 * 2;    // 229 KB
  float* poses_f        = (float*)ws;          ws += (size_t)BATCH * HID_DIM * 4;      // 410 KB
  float* sumsq          = (float*)ws;          ws += (size_t)BATCH * NN * 4;           // 102 KB
  float* expa           = (float*)ws;          ws += (size_t)BATCH * NN * 4;           // 102 KB
  float* D_ws           = (float*)ws;          ws += (size_t)BATCH * 4;
  float* S_ws           = (float*)ws;          ws += (size_t)BATCH * 4;

  k_prep   <<<dim3(PACK_BLOCKS + XG_BLOCKS + 1), 256, 0, stream>>>(
      idx, emb, Ws_w, Ws_b, mlp_w, Bp, x_ws, sumsq, S_ws);
  k_routing<<<dim3(BATCH),        256, 0, stream>>>(idx, times, x_ws, sumsq, Ap, poses_f, expa, D_ws);
  k_gemm<0><<<dim3(NXB, 8),       256, 0, stream>>>(Ap, Bp, mlp_b, D_ws, S_ws, out);
  k_gemm<1><<<dim3(NXB, 8),       256, 0, stream>>>(Ap, Bp, mlp_b, D_ws, S_ws, out);
  k_fix    <<<dim3(BATCH * NN / 4), 256, 0, stream>>>(idx, expa, poses_f, mlp_w, mlp_b, D_ws, S_ws, out);
}

// Round 5
// 266.352 us; speedup vs baseline: 1.0218x; 1.0218x over previous
//
#include <hip/hip_runtime.h>
#include <stdint.h>

#define NUM_E 50000
#define EMBED_DIM 128
#define HID_DIM 200
#define BATCH 512
#define NN 50
#define HPAD 208   // 13*16 (x columns padded)
#define KPAD 224   // 7*32  (scores GEMM K padded)
#define NKT 7      // K tiles of 32
#define NTT2 3136  // N fragment tiles padded: 3136*16 = 50176 = 196*256
#define NXB 196    // column tiles of 256 for scores GEMM
#define PACK_BLOCKS 784    // NTT2/4 (4 n-tiles per block)
#define XG_BLOCKS 400

typedef short s16x8 __attribute__((ext_vector_type(8)));
typedef float f32x4 __attribute__((ext_vector_type(4)));

__device__ inline unsigned short f2bf(float f) {
  union { float f; unsigned u; } v; v.f = f;
  unsigned r = v.u + 0x7FFF + ((v.u >> 16) & 1);
  return (unsigned short)(r >> 16);
}
__device__ inline float bf2f(unsigned short b) {
  union { unsigned u; float f; } v; v.u = ((unsigned)b) << 16;
  return v.f;
}

// async global->LDS, 16B per lane; lds dst = uniform base + lane*16
__device__ __forceinline__ void gl_lds16(const unsigned short* g, unsigned short* l) {
  __builtin_amdgcn_global_load_lds(
      (const __attribute__((address_space(1))) unsigned int*)g,
      (__attribute__((address_space(3))) unsigned int*)l, 16, 0, 0);
}

// ---------------------------------------------------------------------------
// Fused prep kernel:
//   bx in [0, PACK_BLOCKS)            -> coalesced pack of mlp_w into Bp
//   bx in [PACK_BLOCKS, +XG_BLOCKS)   -> x = gather(emb, idx) @ Ws_w^T + Ws_b
//   last block                        -> zero S_ws
// ---------------------------------------------------------------------------
__global__ __launch_bounds__(256) void k_prep(
    const int* __restrict__ idx, const float* __restrict__ emb,
    const float* __restrict__ Ws_w, const float* __restrict__ Ws_b,
    const float* __restrict__ mlp_w,
    unsigned short* __restrict__ Bp, unsigned short* __restrict__ x_ws,
    float* __restrict__ sumsq_ws, float* __restrict__ S_ws)
{
  __shared__ __align__(16) unsigned short smem[12800];  // 25.6 KB, aliased
  const int bx = blockIdx.x;
  const int tid = threadIdx.x;

  if (bx < PACK_BLOCKS) {
    // ---- pack: 4 n-tiles (64 rows x 200 k) per block, via LDS transpose ----
    // load phase: contiguous 64*200 fp32 slab, coalesced float4, cvt to bf16
    const size_t base_f = (size_t)bx * 64 * HID_DIM;   // multiple of 4
    const float4* src4 = (const float4*)(mlp_w + base_f);
    for (int i = tid; i < 3200; i += 256) {
      float4 f;
      if (base_f + 4 * (size_t)i + 4 <= (size_t)NUM_E * HID_DIM) {
        f = src4[i];
      } else {
        f = make_float4(0.f, 0.f, 0.f, 0.f);
      }
      unsigned short t4[4] __attribute__((aligned(8))) = {
        f2bf(f.x), f2bf(f.y), f2bf(f.z), f2bf(f.w)};
      *(uint2*)&smem[i * 4] = *(uint2*)t4;   // LDS row-major [64][200]
    }
    __syncthreads();
    // store phase: 28 fragments x 64 lanes, contiguous 16B stores
    const int nt0 = bx * 4;
    unsigned short* dst = Bp + (size_t)nt0 * NKT * 512;
    for (int s = 0; s < 7; ++s) {
      const int fi = s * 256 + tid;          // [0, 1792)
      const int fr = fi >> 6;                // nt_l*7 + kt
      const int lane = fi & 63;
      const int nt_l = fr / 7, kt = fr - nt_l * 7;
      const int r = nt_l * 16 + (lane & 15);
      const int kb = kt * 32 + (lane >> 4) * 8;
      uint4 val;
      if (kb < HID_DIM) {
        val = *(const uint4*)&smem[r * HID_DIM + kb];
      } else {
        val = make_uint4(0, 0, 0, 0);
      }
      *(uint4*)&dst[(size_t)fi * 8] = val;
    }
    return;
  }
  if (bx >= PACK_BLOCKS + XG_BLOCKS) {
    S_ws[tid] = 0.f;
    S_ws[256 + tid] = 0.f;
    return;
  }

  // ---- xgemm ----
  unsigned short* Al = smem;               // 64*40
  unsigned short* Bl = smem + 64 * 40;     // 208*40
  const int wave = tid >> 6, lane = tid & 63;
  const int q = lane >> 4, l15 = lane & 15;
  const int row0 = (bx - PACK_BLOCKS) * 64;

  f32x4 acc[13];
  for (int i = 0; i < 13; i++) acc[i] = (f32x4){0, 0, 0, 0};

  for (int kt = 0; kt < 4; ++kt) {
    const int k0 = kt * 32;
    {
      const int r = tid >> 2, q4 = tid & 3;
      const int erow = idx[row0 + r];
      const float* src = emb + (size_t)erow * EMBED_DIM + k0 + q4 * 8;
      float4 f0 = *(const float4*)(src);
      float4 f1 = *(const float4*)(src + 4);
      unsigned short tmp[8] __attribute__((aligned(16))) = {
        f2bf(f0.x), f2bf(f0.y), f2bf(f0.z), f2bf(f0.w),
        f2bf(f1.x), f2bf(f1.y), f2bf(f1.z), f2bf(f1.w)};
      *(uint4*)&Al[r * 40 + q4 * 8] = *(uint4*)tmp;
    }
    if (tid < 208) {
      unsigned short tmp[32] __attribute__((aligned(16)));
      if (tid < HID_DIM) {
        const float* src = Ws_w + (size_t)tid * EMBED_DIM + k0;
        for (int j = 0; j < 8; j++) {
          float4 f = *(const float4*)(src + j * 4);
          tmp[j*4+0] = f2bf(f.x); tmp[j*4+1] = f2bf(f.y);
          tmp[j*4+2] = f2bf(f.z); tmp[j*4+3] = f2bf(f.w);
        }
      } else {
        for (int j = 0; j < 32; j++) tmp[j] = 0;
      }
      for (int j = 0; j < 4; j++)
        *(uint4*)&Bl[tid * 40 + j * 8] = *(uint4*)&tmp[j * 8];
    }
    __syncthreads();
    s16x8 a = *(const s16x8*)&Al[(wave * 16 + l15) * 40 + q * 8];
    for (int ni = 0; ni < 13; ++ni) {
      s16x8 bfr = *(const s16x8*)&Bl[(ni * 16 + l15) * 40 + q * 8];
      acc[ni] = __builtin_amdgcn_mfma_f32_16x16x32_bf16(a, bfr, acc[ni], 0, 0, 0);
    }
    __syncthreads();
  }

  float sq[4] = {0, 0, 0, 0};
  for (int ni = 0; ni < 13; ++ni) {
    const int col = ni * 16 + l15;
    const bool cv = col < HID_DIM;
    const float bias = cv ? Ws_b[col] : 0.f;
    for (int p = 0; p < 4; p++) {
      float v = acc[ni][p] + bias;
      if (cv) sq[p] += v * v;
      const int grow = row0 + wave * 16 + q * 4 + p;
      x_ws[(size_t)grow * HPAD + col] = f2bf(cv ? v : 0.f);
    }
  }
  for (int m = 1; m < 16; m <<= 1)
    for (int p = 0; p < 4; p++) sq[p] += __shfl_xor(sq[p], m, 64);
  if (l15 == 0)
    for (int p = 0; p < 4; p++)
      sumsq_ws[row0 + wave * 16 + q * 4 + p] = sq[p];
}

// ---------------------------------------------------------------------------
// Kernel A2: routing. Emits Ap (A-fragment layout), fp32 poses, expa, D_b.
// ---------------------------------------------------------------------------
__global__ __launch_bounds__(256) void k_routing(
    const int* __restrict__ idx, const int* __restrict__ times,
    const unsigned short* __restrict__ x_ws, const float* __restrict__ sumsq_ws,
    unsigned short* __restrict__ Ap, float* __restrict__ poses_f,
    float* __restrict__ expa_ws, float* __restrict__ D_ws)
{
  __shared__ float u[NN * 201];
  __shared__ float cc[NN];
  __shared__ float bb[NN];
  __shared__ float vv[HID_DIM];
  __shared__ float nrm[NN];
  __shared__ int   sidx[NN];
  __shared__ float red[4];
  __shared__ float scaleS;
  const int tid = threadIdx.x;
  const int b = blockIdx.x;

  if (tid < NN) {
    nrm[tid] = fmaxf(sqrtf(sumsq_ws[b * NN + tid]), 1e-12f);
    sidx[tid] = idx[b * NN + tid];
    bb[tid] = 2.0f / (1.0f + (float)times[b * NN + tid]);
  }
  __syncthreads();
  // u-load: 4 threads per row, 50 cols each
  const int un = tid >> 2, uc0 = (tid & 3) * 50;
  if (un < NN) {
    const float inv = 1.0f / nrm[un];
    const unsigned short* xs = &x_ws[(size_t)(b * NN + un) * HPAD + uc0];
    for (int j = 0; j < 50; j++) u[un * 201 + uc0 + j] = bf2f(xs[j]) * inv;
  }
  __syncthreads();

  for (int it = 0; it < 3; ++it) {
    if (tid < 64) {
      float x = (tid < NN) ? bb[tid] : -1e30f;
      float m = x;
      for (int d = 1; d < 64; d <<= 1) m = fmaxf(m, __shfl_xor(m, d, 64));
      float e = (tid < NN) ? __expf(x - m) : 0.f;
      float s = e;
      for (int d = 1; d < 64; d <<= 1) s += __shfl_xor(s, d, 64);
      if (tid < NN) cc[tid] = e * (float)NN / s;
    }
    __syncthreads();
    float sh = 0.f;
    if (tid < HID_DIM)
      for (int n = 0; n < NN; n++) sh += cc[n] * u[n * 201 + tid];
    float sq = (tid < HID_DIM) ? sh * sh : 0.f;
    for (int d = 1; d < 64; d <<= 1) sq += __shfl_xor(sq, d, 64);
    if ((tid & 63) == 0) red[tid >> 6] = sq;
    __syncthreads();
    if (tid == 0) {
      const float t = red[0] + red[1] + red[2] + red[3];
      scaleS = t / (1.0f + t) / sqrtf(t + 1e-9f);
    }
    __syncthreads();
    if (tid < HID_DIM) vv[tid] = scaleS * sh;
    __syncthreads();
    if (it < 2) {
      float d = 0.f;
      if (un < NN)
        for (int j = 0; j < 50; j++) d += u[un * 201 + uc0 + j] * vv[uc0 + j];
      d += __shfl_xor(d, 1, 64);
      d += __shfl_xor(d, 2, 64);
      if (un < NN && (tid & 3) == 0) bb[un] += d;
      __syncthreads();
    }
  }
  // poses scattered into A-fragment layout (zero-padded to KPAD)
  if (tid < KPAD) {
    const float val = (tid < HID_DIM) ? vv[tid] : 0.f;
    const int kt = tid >> 5, rem = tid & 31, q = rem >> 3, j = rem & 7;
    const int mt = b >> 4, l15 = b & 15;
    Ap[(size_t)(((mt * NKT + kt) * 64) + q * 16 + l15) * 8 + j] = f2bf(val);
  }
  if (tid < HID_DIM) poses_f[b * HID_DIM + tid] = vv[tid];
  // dedup of idx within row; D_b = NUM_E + sum_unique (exp(a)-1)
  if (tid < 64) {
    float a = 0.f; int first = 1;
    const int my = (tid < NN) ? sidx[tid] : -1;
    if (tid < NN) {
      for (int n = 0; n < NN; n++)
        if (sidx[n] == my) { a += cc[n]; if (n < tid) first = 0; }
      expa_ws[b * NN + tid] = __expf(a);
    }
    float contrib = (tid < NN && first) ? (__expf(a) - 1.0f) : 0.f;
    for (int d = 1; d < 64; d <<= 1) contrib += __shfl_xor(contrib, d, 64);
    if (tid == 0) D_ws[b] = (float)NUM_E + contrib;
  }
}

// ---------------------------------------------------------------------------
// Kernel G: GEMM, block tile 64M x 256N, K=224. XCD-aware 1-D grid of 1600:
// xb = id % 200 (column tile, skip >=196), yb = id / 200. Stride 200 == 0
// mod 8 keeps all 8 row-blocks of a column-slice on one XCD -> Bp slice
// (~2.8 MB) stays L2-resident within and across passes.
// PASS 0: S_b += sum exp(score).  PASS 1: out = log(0.5/D + 0.5*exp(s)/S).
// ---------------------------------------------------------------------------
template<int PASS>
__global__ __launch_bounds__(256, 4) void k_gemm(
    const unsigned short* __restrict__ Ap, const unsigned short* __restrict__ Bp,
    const float* __restrict__ mlp_b, const float* __restrict__ D_ws,
    float* __restrict__ S_ws, float* __restrict__ out)
{
  __shared__ __align__(16) unsigned short Bs[16 * 512];  // 16 KB
  __shared__ float red[256];
  const int id = blockIdx.x;
  const int yb = id / 200;
  const int xb = id - yb * 200;
  if (xb >= NXB) return;
  const int tid = threadIdx.x;
  const int w = tid >> 6, lane = tid & 63;
  const int q = lane >> 4, l15 = lane & 15;
  const int mt0 = yb * 4;
  const int m0 = yb * 64;
  const int ntb = xb * 16 + w * 4;   // wave's first nt tile

  if (PASS == 1 && tid < 64) {
    red[tid]      = 0.5f / D_ws[m0 + tid];
    red[64 + tid] = 0.5f / S_ws[m0 + tid];
  }
  float bias[4];
  #pragma unroll
  for (int nl = 0; nl < 4; ++nl) {
    const int col = (ntb + nl) * 16 + l15;
    bias[nl] = (col < NUM_E) ? mlp_b[col] : 0.f;
  }

  const unsigned short* apBase = Ap + (size_t)mt0 * NKT * 512;

  f32x4 acc[4][4];
  #pragma unroll
  for (int i = 0; i < 4; i++)
    #pragma unroll
    for (int j = 0; j < 4; j++) acc[i][j] = (f32x4){0, 0, 0, 0};

  for (int kt = 0; kt < NKT; ++kt) {
    #pragma unroll
    for (int nl = 0; nl < 4; ++nl)
      gl_lds16(Bp + ((size_t)(ntb + nl) * NKT + kt) * 512 + lane * 8,
               &Bs[(w * 4 + nl) * 512]);
    s16x8 a[4];
    #pragma unroll
    for (int mi = 0; mi < 4; ++mi)
      a[mi] = *(const s16x8*)&apBase[((mi * NKT + kt) * 64 + lane) * 8];
    __syncthreads();   // drains gl_lds (vmcnt 0) + the a-loads
    s16x8 bfr[4];
    #pragma unroll
    for (int nl = 0; nl < 4; ++nl)
      bfr[nl] = *(const s16x8*)&Bs[((w * 4 + nl) * 64 + lane) * 8];
    #pragma unroll
    for (int nl = 0; nl < 4; ++nl)
      #pragma unroll
      for (int mi = 0; mi < 4; ++mi)
        acc[mi][nl] = __builtin_amdgcn_mfma_f32_16x16x32_bf16(a[mi], bfr[nl], acc[mi][nl], 0, 0, 0);
    __syncthreads();   // all waves done reading Bs before next staging
  }

  if (PASS == 0) {
    float rs[4][4];
    #pragma unroll
    for (int mi = 0; mi < 4; mi++)
      #pragma unroll
      for (int p = 0; p < 4; p++) rs[mi][p] = 0.f;
    #pragma unroll
    for (int mi = 0; mi < 4; ++mi)
      #pragma unroll
      for (int nl = 0; nl < 4; ++nl) {
        const int col = (ntb + nl) * 16 + l15;
        #pragma unroll
        for (int p = 0; p < 4; p++) {
          const float v = acc[mi][nl][p] + bias[nl];
          rs[mi][p] += (col < NUM_E) ? __expf(v) : 0.f;
        }
      }
    #pragma unroll
    for (int m = 1; m < 16; m <<= 1)
      for (int mi = 0; mi < 4; mi++)
        for (int p = 0; p < 4; p++)
          rs[mi][p] += __shfl_xor(rs[mi][p], m, 64);
    if (l15 == 0)
      for (int mi = 0; mi < 4; mi++)
        for (int p = 0; p < 4; p++)
          red[w * 64 + mi * 16 + q * 4 + p] = rs[mi][p];
    __syncthreads();
    if (tid < 64)
      atomicAdd(&S_ws[m0 + tid],
                red[tid] + red[64 + tid] + red[128 + tid] + red[192 + tid]);
  } else {
    #pragma unroll
    for (int mi = 0; mi < 4; ++mi) {
      #pragma unroll
      for (int p = 0; p < 4; p++) {
        const int rl = mi * 16 + q * 4 + p;
        const float invD = red[rl];
        const float invS = red[64 + rl];
        const int row = m0 + rl;
        #pragma unroll
        for (int nl = 0; nl < 4; ++nl) {
          const int col = (ntb + nl) * 16 + l15;
          if (col < NUM_E) {
            const float v = acc[mi][nl][p] + bias[nl];
            out[(size_t)row * NUM_E + col] = __logf(fmaf(__expf(v), invS, invD));
          }
        }
      }
    }
  }
}

// ---------------------------------------------------------------------------
// Kernel D: fixup history positions; recompute score via fp32 dot product.
// One wave per (b, slot). Duplicate idx -> identical values, benign race.
// ---------------------------------------------------------------------------
__global__ __launch_bounds__(256) void k_fix(
    const int* __restrict__ idx, const float* __restrict__ expa,
    const float* __restrict__ poses_f, const float* __restrict__ mlp_w,
    const float* __restrict__ mlp_b, const float* __restrict__ D_ws,
    const float* __restrict__ S_ws, float* __restrict__ out)
{
  const int t = blockIdx.x * 4 + (threadIdx.x >> 6);
  const int lane = threadIdx.x & 63;
  if (t >= BATCH * NN) return;
  const int b = t / NN;
  const int j = idx[t];
  float dot = 0.f;
  for (int h = lane; h < HID_DIM; h += 64)
    dot += poses_f[b * HID_DIM + h] * mlp_w[(size_t)j * HID_DIM + h];
  for (int m = 1; m < 64; m <<= 1) dot += __shfl_xor(dot, m, 64);
  if (lane == 0) {
    const float s = dot + mlp_b[j];
    out[(size_t)b * NUM_E + j] = __logf(0.5f * expa[t] / D_ws[b] +
                                        0.5f * __expf(s) / S_ws[b]);
  }
}

extern "C" void kernel_launch(void* const* d_in, const int* in_sizes, int n_in,
                              void* d_out, int out_size, void* d_ws, size_t ws_size,
                              hipStream_t stream) {
  const int*   idx   = (const int*)d_in[0];
  const int*   times = (const int*)d_in[1];
  const float* emb   = (const float*)d_in[2];
  const float* Ws_w  = (const float*)d_in[3];
  const float* Ws_b  = (const float*)d_in[4];
  const float* mlp_w = (const float*)d_in[5];
  const float* mlp_b = (const float*)d_in[6];
  float* out = (float*)d_out;

  char* ws = (char*)d_ws;
  unsigned short* Bp    = (unsigned short*)ws; ws += (size_t)NTT2 * NKT * 64 * 8 * 2;  // 22.5 MB
  unsigned short* x_ws  = (unsigned short*)ws; ws += (size_t)BATCH * NN * HPAD * 2;    // 10.65 MB
  unsigned short* Ap    = (unsigned short*)ws; ws += (size_t)32 * NKT * 64 * 8 * 2;    // 229 KB
  float* poses_f        = (float*)ws;          ws += (size_t)BATCH * HID_DIM * 4;      // 410 KB
  float* sumsq          = (float*)ws;          ws += (size_t)BATCH * NN * 4;           // 102 KB
  float* expa           = (float*)ws;          ws += (size_t)BATCH * NN * 4;           // 102 KB
  float* D_ws           = (float*)ws;          ws += (size_t)BATCH * 4;
  float* S_ws           = (float*)ws;          ws += (size_t)BATCH * 4;

  k_prep   <<<dim3(PACK_BLOCKS + XG_BLOCKS + 1), 256, 0, stream>>>(
      idx, emb, Ws_w, Ws_b, mlp_w, Bp, x_ws, sumsq, S_ws);
  k_routing<<<dim3(BATCH),        256, 0, stream>>>(idx, times, x_ws, sumsq, Ap, poses_f, expa, D_ws);
  k_gemm<0><<<dim3(1600),         256, 0, stream>>>(Ap, Bp, mlp_b, D_ws, S_ws, out);
  k_gemm<1><<<dim3(1600),         256, 0, stream>>>(Ap, Bp, mlp_b, D_ws, S_ws, out);
  k_fix    <<<dim3(BATCH * NN / 4), 256, 0, stream>>>(idx, expa, poses_f, mlp_w, mlp_b, D_ws, S_ws, out);
}